// Round 1
// baseline (329.906 us; speedup 1.0000x reference)
//
#include <hip/hip_runtime.h>

// QNet forward, MI355X. Round 9.
// enc: REWRITTEN as barrier-free per-wave DMA pipeline.
//      grid (16,32), 4 waves/block, each wave streams 8 tiles x 16 rows with
//      double-buffered global_load_lds (width=16) f32 obs slabs + counted
//      s_waitcnt vmcnt(8). XOR chunk swizzle (src-side + read-side) kills the
//      512B-row-stride bank conflict. x/h transpose slabs aliased into the
//      consumed obs buffer. No __syncthreads in enc at all.
// dec: unchanged from round 8 (evidence first: need its counters once enc
//      stops dominating).
// B=8192, A=32, NOBS=128, NH1=128, HX=64, NACT=16. fp32 in/out.

#define NB   8192
#define NA   32
#define NOBS 128
#define NH1  128
#define HXX  64
#define NACT 16

typedef _Float16 half8 __attribute__((ext_vector_type(8)));
typedef _Float16 half4 __attribute__((ext_vector_type(4)));
typedef float    floatx4 __attribute__((ext_vector_type(4)));

#define MFMA16(af, bf, c) __builtin_amdgcn_mfma_f32_16x16x32_f16((af), (bf), (c), 0, 0, 0)

// ws offsets in halfs
#define HWS_OFF 0
#define W1P_OFF (NB * NA * HXX)                    // 16,777,216
#define W1P_CNT (NA * 8 * 4 * 512)                 // 524,288
#define W2P_OFF (W1P_OFF + W1P_CNT)
#define W2P_CNT (NA * 4 * 4 * 512)                 // 262,144
#define WCP_OFF (W2P_OFF + W2P_CNT)
#define WCP_CNT (NA * 4 * 4 * 512)                 // 262,144
#define WDP_OFF (WCP_OFF + WCP_CNT)
#define WDP_CNT (NA * 1 * 2 * 512)                 // 32,768
#define MN_OFF  (WDP_OFF + WDP_CNT)                // 17,858,560 (f32 x 1024)
#define PACK_TOTAL (W1P_CNT + W2P_CNT + WCP_CNT + WDP_CNT)   // 1,081,344

#define HSTR 2056                                  // dec row slab (2048+8 pad)
#define DEC_LDS (16 * HSTR * 2)                    // 65,792 B

// enc pipeline geometry
#define ENC_ROWS_BLK 512                           // rows per block
#define ENC_TILES    8                             // 8 tiles x 64 rows (16/wave)
#define ENC_SLAB     16384                         // bytes of LDS per wave (2x8KB)
#define ENC_LDS      (4 * ENC_SLAB)                // 65,536 B

using gas1p = const __attribute__((address_space(1))) void*;
using las3p = __attribute__((address_space(3))) void*;

__device__ __forceinline__ float fast_tanh(float x) {
    x = fminf(fmaxf(x, -10.f), 10.f);
    float e2 = __expf(2.f * x);
    return (e2 - 1.f) / (e2 + 1.f);
}

// ---------------------------------------------------------------------------
// Pack: fp32 weights -> f16 MFMA B-fragments; plus normalized comm mask (f32).
// frag(a,nt,s)[l*8+j] = W[a][s*32+(l>>4)*8+j][nt*16+(l&15)]
// ---------------------------------------------------------------------------
extern "C" __global__ void pack_kernel(const float* __restrict__ W1,
                                       const float* __restrict__ W2,
                                       const float* __restrict__ Wc,
                                       const float* __restrict__ Wd,
                                       const int*   __restrict__ cmask,
                                       _Float16* __restrict__ ws)
{
    int e = blockIdx.x * 256 + threadIdx.x;
    if (e >= PACK_TOTAL + NA * NA) return;
    if (e >= PACK_TOTAL) {                       // normalized mask -> f32
        int r = e - PACK_TOTAL, i = r >> 5, j = r & 31;
        int c = 0;
        for (int jj = 0; jj < NA; ++jj) c += (jj != i && cmask[i * NA + jj]) ? 1 : 0;
        float v = 0.f;
        if (j != i && cmask[i * NA + j]) v = 1.0f / (float)(c > 1 ? c : 1);
        ((float*)(ws + MN_OFF))[r] = v;
        return;
    }
    const float* src; _Float16* dst; int K, N, NT, NS, r;
    if (e < W1P_CNT) {
        src = W1; dst = ws + W1P_OFF; K = 128; N = 128; NT = 8; NS = 4; r = e;
    } else if (e < W1P_CNT + W2P_CNT) {
        src = W2; dst = ws + W2P_OFF; K = 128; N = 64; NT = 4; NS = 4; r = e - W1P_CNT;
    } else if (e < W1P_CNT + W2P_CNT + WCP_CNT) {
        src = Wc; dst = ws + WCP_OFF; K = 128; N = 64; NT = 4; NS = 4; r = e - W1P_CNT - W2P_CNT;
    } else {
        src = Wd; dst = ws + WDP_OFF; K = 64; N = 16; NT = 1; NS = 2; r = e - W1P_CNT - W2P_CNT - WCP_CNT;
    }
    int j = r & 7, l = (r >> 3) & 63;
    int rest = r >> 9;
    int s  = rest % NS; rest /= NS;
    int nt = rest % NT; rest /= NT;
    int a  = rest;
    int k = s * 32 + (l >> 4) * 8 + j;
    int n = nt * 16 + (l & 15);
    dst[r] = (_Float16)src[((size_t)a * K + k) * N + n];
}

// ---------------------------------------------------------------------------
// Encoder: h = relu(relu(obs@W1+b1)@W2+b2) -> ws (f16, [b][a][c])
// grid (16, 32), block 256 (4 waves). Per-wave independent pipeline:
//   tile t: issue DMA(t+1) -> other buf; s_waitcnt vmcnt(8); GEMM1 from
//   swizzled f32 slab; x (f16) aliased into consumed slab; GEMM2; h staged;
//   coalesced b128 stores. No barriers; vmcnt is per-wave.
// LDS swizzle: stored chunk c holds global chunk c^(row&7); reads XOR the
// same (involution). 16B chunk granularity matches DMA lane granularity.
// ---------------------------------------------------------------------------
extern "C" __global__ __launch_bounds__(256, 2)
void enc_kernel(const float* __restrict__ obs,
                const float* __restrict__ b1,
                const float* __restrict__ b2,
                const _Float16* __restrict__ W1p,
                const _Float16* __restrict__ W2p,
                _Float16* __restrict__ hws)
{
    extern __shared__ char smem[];

    const int tid  = threadIdx.x;
    const int a    = blockIdx.y;
    const int w    = tid >> 6, l = tid & 63;
    const int lm   = l & 15, lq = l >> 4;
    const int hrow = l >> 5;          // DMA: row parity within 2-row chunk
    const int cch  = l & 31;          // DMA: stored 16B-chunk index
    char* SB = smem + w * ENC_SLAB;   // this wave's 16KB double buffer

    const int rowb = blockIdx.x * ENC_ROWS_BLK + w * 16;  // wave row base

    float b1v[8], b2v[4];
    #pragma unroll
    for (int nt = 0; nt < 8; ++nt) b1v[nt] = b1[a * NH1 + nt * 16 + lm];
    #pragma unroll
    for (int nt = 0; nt < 4; ++nt) b2v[nt] = b2[a * HXX + nt * 16 + lm];

    // Issue one tile's 8KB via 8 wave-level DMAs (1KB each).
    // LDS linear slot (i*1024 + lane*16) = row (2i+hrow), chunk (l&31);
    // global source pre-swizzled: fetch chunk cch ^ (row&7).
    auto issue = [&](int t, int q) {
        #pragma unroll
        for (int i = 0; i < 8; ++i) {
            const int r = 2 * i + hrow;
            const int g = cch ^ (r & 7);
            const float* gp = obs + ((size_t)(rowb + t * 64 + r) * NA + a) * NOBS + g * 4;
            __builtin_amdgcn_global_load_lds((gas1p)gp,
                                             (las3p)(SB + q * 8192 + i * 1024),
                                             16, 0, 0);
        }
    };

    int p = 0;
    issue(0, 0);

    #pragma unroll 2
    for (int t = 0; t < ENC_TILES; ++t) {
        if (t < ENC_TILES - 1) {
            // drain wave's LDS queue before DMA may overwrite re-used buffer
            asm volatile("s_waitcnt lgkmcnt(0)" ::: "memory");
            issue(t + 1, p ^ 1);
            // newest 8 vmem ops = batch t+1; waiting to 8 drains batch t
            asm volatile("s_waitcnt vmcnt(8)" ::: "memory");
        } else {
            asm volatile("s_waitcnt vmcnt(0)" ::: "memory");
        }
        __builtin_amdgcn_sched_barrier(0);

        const char* SBp = SB + p * 8192;
        _Float16*   X   = (_Float16*)(SB + p * 8192);  // aliased after GEMM1
        const int   rx  = lm & 7;

        // ---- GEMM1: x = obs @ W1 (1 m-tile x 8 n-tiles, K=128)
        floatx4 acc1[8];
        #pragma unroll
        for (int nt = 0; nt < 8; ++nt) acc1[nt] = (floatx4){0.f, 0.f, 0.f, 0.f};
        #pragma unroll
        for (int s = 0; s < 4; ++s) {
            const int c0 = s * 8 + lq * 2;
            floatx4 f0 = *(const floatx4*)(SBp + lm * 512 + (((c0    ) ^ rx) << 4));
            floatx4 f1 = *(const floatx4*)(SBp + lm * 512 + (((c0 + 1) ^ rx) << 4));
            half8 af;
            af[0] = (_Float16)f0[0]; af[1] = (_Float16)f0[1];
            af[2] = (_Float16)f0[2]; af[3] = (_Float16)f0[3];
            af[4] = (_Float16)f1[0]; af[5] = (_Float16)f1[1];
            af[6] = (_Float16)f1[2]; af[7] = (_Float16)f1[3];
            #pragma unroll
            for (int nt = 0; nt < 8; ++nt) {
                half8 bf = *(const half8*)&W1p[(((a * 8 + nt) * 4 + s) * 512) + l * 8];
                acc1[nt] = MFMA16(af, bf, acc1[nt]);
            }
        }
        // x (relu) into the consumed slab, transposed layout [row][136]
        #pragma unroll
        for (int nt = 0; nt < 8; ++nt)
            #pragma unroll
            for (int v = 0; v < 4; ++v) {
                float xv = fmaxf(acc1[nt][v] + b1v[nt], 0.f);
                X[(lq * 4 + v) * 136 + nt * 16 + lm] = (_Float16)xv;
            }

        // ---- GEMM2: h = X @ W2 (1 m-tile x 4 n-tiles)
        floatx4 acc2[4];
        #pragma unroll
        for (int nt = 0; nt < 4; ++nt) acc2[nt] = (floatx4){0.f, 0.f, 0.f, 0.f};
        #pragma unroll
        for (int s = 0; s < 4; ++s) {
            half8 af2 = *(const half8*)&X[lm * 136 + s * 32 + lq * 8];
            #pragma unroll
            for (int nt = 0; nt < 4; ++nt) {
                half8 bf = *(const half8*)&W2p[(((a * 4 + nt) * 4 + s) * 512) + l * 8];
                acc2[nt] = MFMA16(af2, bf, acc2[nt]);
            }
        }
        #pragma unroll
        for (int nt = 0; nt < 4; ++nt)
            #pragma unroll
            for (int v = 0; v < 4; ++v) {
                float hv = fmaxf(acc2[nt][v] + b2v[nt], 0.f);
                X[(lq * 4 + v) * 136 + nt * 16 + lm] = (_Float16)hv;
            }

        // ---- epilogue: coalesced b128 h stores (16 rows x 8 chunks)
        {
            const int rr = l >> 2, cc = l & 3;
            #pragma unroll
            for (int q2 = 0; q2 < 2; ++q2) {
                const int chunk = cc + 4 * q2;
                half8 hv8 = *(const half8*)&X[rr * 136 + chunk * 8];
                *(half8*)&hws[((size_t)(rowb + t * 64 + rr) * NA + a) * HXX + chunk * 8] = hv8;
            }
        }
        p ^= 1;
    }
}

// ---------------------------------------------------------------------------
// Decoder: comm masked-mean + tanh([h|comm]@Wc+bc) @ Wd + bd.
// grid 512, block 512 (8 waves). Block = 16 batch rows x 32 agents.
// H (LDS): [row][agent*64+c], row slab HSTR halfs. Wave w owns agents
// 4w..4w+3, full 16-row m-tiles. comm lives in A-frag registers (hacc):
// frag_comm(i,s) = sum_j Mn[i][j] * frag_h(j, s-2)  (fragment linearity).
// h2 in C-layout regs across nt loop; single LDS write for Wd GEMM.
// ---------------------------------------------------------------------------
extern "C" __global__ __launch_bounds__(512)
void dec_kernel(const _Float16* __restrict__ hws,
                const float* __restrict__ MnG,
                const float* __restrict__ bc,
                const float* __restrict__ bd,
                const _Float16* __restrict__ Wcp,
                const _Float16* __restrict__ Wdp,
                float* __restrict__ out)
{
    extern __shared__ char smem[];
    _Float16* H = (_Float16*)smem;   // 16 x HSTR

    const int t  = threadIdx.x;
    const int b0 = blockIdx.x * 16;

    {   // stage h tile: 16 rows x 32 ag x 64 ch = 4096 uint4, coalesced
        const uint4* src = (const uint4*)(hws + (size_t)b0 * NA * HXX);
        #pragma unroll
        for (int it = 0; it < 8; ++it) {
            int idx = it * 512 + t;
            int row = idx >> 8, rem = idx & 255;
            *(uint4*)&H[row * HSTR + rem * 8] = src[idx];
        }
    }
    __syncthreads();

    const int w = t >> 6, l = t & 63, lm = l & 15, lq = l >> 4;

    // ---- comm into A-frag registers (reads ALL rows; barrier after)
    half8 hacc[4][2];
    #pragma unroll
    for (int g = 0; g < 4; ++g)
        #pragma unroll
        for (int sb = 0; sb < 2; ++sb)
            #pragma unroll
            for (int q = 0; q < 8; ++q) hacc[g][sb][q] = (_Float16)0.f;

    #pragma unroll 4
    for (int j = 0; j < NA; ++j) {
        half8 v0 = *(const half8*)&H[lm * HSTR + j * 64 + lq * 8];
        half8 v1 = *(const half8*)&H[lm * HSTR + j * 64 + 32 + lq * 8];
        #pragma unroll
        for (int g = 0; g < 4; ++g) {
            int ag = __builtin_amdgcn_readfirstlane(w * 4 + g);
            _Float16 mh = (_Float16)MnG[ag * NA + j];   // s_load, wave-uniform
            hacc[g][0] += v0 * mh;
            hacc[g][1] += v1 * mh;
        }
    }
    __syncthreads();   // all comm reads done before any h2 overwrite
    // From here each wave touches only its own agents' columns.

    // ---- Wc GEMM per n-tile; h2 kept in C-layout regs
    half4 h2r[4][4];
    #pragma unroll
    for (int nt = 0; nt < 4; ++nt) {
        floatx4 acc[4];
        #pragma unroll
        for (int g = 0; g < 4; ++g) acc[g] = (floatx4){0.f, 0.f, 0.f, 0.f};
        #pragma unroll
        for (int s = 0; s < 4; ++s) {
            #pragma unroll
            for (int g = 0; g < 4; ++g) {
                int ag = w * 4 + g;
                half8 af = (s < 2)
                    ? *(const half8*)&H[lm * HSTR + ag * 64 + s * 32 + lq * 8]
                    : hacc[g][s - 2];
                half8 bf = *(const half8*)&Wcp[(((ag * 4 + nt) * 4 + s) * 512) + l * 8];
                acc[g] = MFMA16(af, bf, acc[g]);
            }
        }
        #pragma unroll
        for (int g = 0; g < 4; ++g) {
            int ag = w * 4 + g;
            float bcv = bc[ag * HXX + nt * 16 + lm];
            #pragma unroll
            for (int v = 0; v < 4; ++v)
                h2r[g][nt][v] = (_Float16)fast_tanh(acc[g][v] + bcv);
        }
    }

    // write h2 over own agents' h (all Wc reads of those columns are done)
    #pragma unroll
    for (int g = 0; g < 4; ++g) {
        int ag = w * 4 + g;
        #pragma unroll
        for (int nt = 0; nt < 4; ++nt)
            #pragma unroll
            for (int v = 0; v < 4; ++v)
                H[(lq * 4 + v) * HSTR + ag * 64 + nt * 16 + lm] = h2r[g][nt][v];
    }
    // wave-internal LDS RAW -> compiler lgkmcnt; no cross-wave access

    // ---- Wd GEMM: K=64, N=16
    floatx4 acc3[4];
    #pragma unroll
    for (int g = 0; g < 4; ++g) acc3[g] = (floatx4){0.f, 0.f, 0.f, 0.f};
    #pragma unroll
    for (int s = 0; s < 2; ++s) {
        #pragma unroll
        for (int g = 0; g < 4; ++g) {
            int ag = w * 4 + g;
            half8 af = *(const half8*)&H[lm * HSTR + ag * 64 + s * 32 + lq * 8];
            half8 bf = *(const half8*)&Wdp[((ag * 2 + s) * 512) + l * 8];
            acc3[g] = MFMA16(af, bf, acc3[g]);
        }
    }

    #pragma unroll
    for (int g = 0; g < 4; ++g) {
        int ag = w * 4 + g;
        float bdv = bd[ag * NACT + lm];
        #pragma unroll
        for (int v = 0; v < 4; ++v) {
            int row = lq * 4 + v;
            out[((size_t)(b0 + row) * NA + ag) * NACT + lm] = acc3[g][v] + bdv;
        }
    }
}

// ---------------------------------------------------------------------------
extern "C" void kernel_launch(void* const* d_in, const int* in_sizes, int n_in,
                              void* d_out, int out_size, void* d_ws, size_t ws_size,
                              hipStream_t stream)
{
    const float* obs = (const float*)d_in[0];
    const float* W1  = (const float*)d_in[1];
    const float* b1  = (const float*)d_in[2];
    const float* W2  = (const float*)d_in[3];
    const float* b2  = (const float*)d_in[4];
    const float* Wc  = (const float*)d_in[7];
    const float* bc  = (const float*)d_in[8];
    const float* Wd  = (const float*)d_in[9];
    const float* bd  = (const float*)d_in[10];
    const int*   cm  = (const int*)d_in[11];

    float*    outp = (float*)d_out;
    _Float16* ws   = (_Float16*)d_ws;

    _Float16* hws = ws + HWS_OFF;
    _Float16* W1p = ws + W1P_OFF;
    _Float16* W2p = ws + W2P_OFF;
    _Float16* Wcp = ws + WCP_OFF;
    _Float16* Wdp = ws + WDP_OFF;
    const float* MnG = (const float*)(ws + MN_OFF);

    hipLaunchKernelGGL(pack_kernel, dim3((PACK_TOTAL + NA * NA + 255) / 256),
                       dim3(256), 0, stream, W1, W2, Wc, Wd, cm, ws);

    (void)hipFuncSetAttribute((const void*)enc_kernel,
                              hipFuncAttributeMaxDynamicSharedMemorySize, ENC_LDS);
    hipLaunchKernelGGL(enc_kernel, dim3(NB / ENC_ROWS_BLK, NA), dim3(256), ENC_LDS,
                       stream, obs, b1, b2, W1p, W2p, hws);

    (void)hipFuncSetAttribute((const void*)dec_kernel,
                              hipFuncAttributeMaxDynamicSharedMemorySize, DEC_LDS);
    hipLaunchKernelGGL(dec_kernel, dim3(NB / 16), dim3(512), DEC_LDS, stream,
                       hws, MnG, bc, bd, Wcp, Wdp, outp);
}

// Round 2
// 271.748 us; speedup vs baseline: 1.2140x; 1.2140x over previous
//
#include <hip/hip_runtime.h>

// QNet forward, MI355X. Round 10.
// enc: per-wave DMA pipeline, fixed from round 9:
//      - ALL weight fragments (W1: 128 VGPR, W2: 64 VGPR) hoisted to registers
//        pre-loop with asm keep-alives -> loop contains ZERO global loads ->
//        hand-counted vmcnt is the only vmem wait (round-9 bug: compiler
//        vmcnt(j<8) for in-loop weight loads drained the prefetch DMAs).
//      - no unroll-2 (round-9 spill: symmetric +43MB FETCH/WRITE = scratch).
//      - vmcnt peel 8/10/2 so h-stores of tile t-1 are NOT waited on.
//      grid (8,32), 1 block/CU, 4 indep waves x 16 tiles x 16 rows,
//      2x8KB LDS slabs/wave, XOR chunk swizzle both sides. No barriers.
// dec: unchanged (need its counters once enc stops dominating).
// B=8192, A=32, NOBS=128, NH1=128, HX=64, NACT=16. fp32 in/out.

#define NB   8192
#define NA   32
#define NOBS 128
#define NH1  128
#define HXX  64
#define NACT 16

typedef _Float16 half8 __attribute__((ext_vector_type(8)));
typedef _Float16 half4 __attribute__((ext_vector_type(4)));
typedef float    floatx4 __attribute__((ext_vector_type(4)));

#define MFMA16(af, bf, c) __builtin_amdgcn_mfma_f32_16x16x32_f16((af), (bf), (c), 0, 0, 0)
#define H8(x) __builtin_bit_cast(half8, (x))

// ws offsets in halfs
#define HWS_OFF 0
#define W1P_OFF (NB * NA * HXX)                    // 16,777,216
#define W1P_CNT (NA * 8 * 4 * 512)                 // 524,288
#define W2P_OFF (W1P_OFF + W1P_CNT)
#define W2P_CNT (NA * 4 * 4 * 512)                 // 262,144
#define WCP_OFF (W2P_OFF + W2P_CNT)
#define WCP_CNT (NA * 4 * 4 * 512)                 // 262,144
#define WDP_OFF (WCP_OFF + WCP_CNT)
#define WDP_CNT (NA * 1 * 2 * 512)                 // 32,768
#define MN_OFF  (WDP_OFF + WDP_CNT)                // 17,858,560 (f32 x 1024)
#define PACK_TOTAL (W1P_CNT + W2P_CNT + WCP_CNT + WDP_CNT)   // 1,081,344

#define HSTR 2056                                  // dec row slab (2048+8 pad)
#define DEC_LDS (16 * HSTR * 2)                    // 65,792 B

// enc pipeline geometry
#define ENC_TILES 16                               // tiles per wave
#define ENC_WROWS 256                              // rows per wave
#define ENC_BROWS 1024                             // rows per block
#define ENC_SLAB  16384                            // 2 x 8KB per wave
#define ENC_LDS   (4 * ENC_SLAB)                   // 65,536 B

using gas1p = const __attribute__((address_space(1))) void*;
using las3p = __attribute__((address_space(3))) void*;

__device__ __forceinline__ float fast_tanh(float x) {
    x = fminf(fmaxf(x, -10.f), 10.f);
    float e2 = __expf(2.f * x);
    return (e2 - 1.f) / (e2 + 1.f);
}

// ---------------------------------------------------------------------------
// Pack: fp32 weights -> f16 MFMA B-fragments; plus normalized comm mask (f32).
// frag(a,nt,s)[l*8+j] = W[a][s*32+(l>>4)*8+j][nt*16+(l&15)]
// ---------------------------------------------------------------------------
extern "C" __global__ void pack_kernel(const float* __restrict__ W1,
                                       const float* __restrict__ W2,
                                       const float* __restrict__ Wc,
                                       const float* __restrict__ Wd,
                                       const int*   __restrict__ cmask,
                                       _Float16* __restrict__ ws)
{
    int e = blockIdx.x * 256 + threadIdx.x;
    if (e >= PACK_TOTAL + NA * NA) return;
    if (e >= PACK_TOTAL) {                       // normalized mask -> f32
        int r = e - PACK_TOTAL, i = r >> 5, j = r & 31;
        int c = 0;
        for (int jj = 0; jj < NA; ++jj) c += (jj != i && cmask[i * NA + jj]) ? 1 : 0;
        float v = 0.f;
        if (j != i && cmask[i * NA + j]) v = 1.0f / (float)(c > 1 ? c : 1);
        ((float*)(ws + MN_OFF))[r] = v;
        return;
    }
    const float* src; _Float16* dst; int K, N, NT, NS, r;
    if (e < W1P_CNT) {
        src = W1; dst = ws + W1P_OFF; K = 128; N = 128; NT = 8; NS = 4; r = e;
    } else if (e < W1P_CNT + W2P_CNT) {
        src = W2; dst = ws + W2P_OFF; K = 128; N = 64; NT = 4; NS = 4; r = e - W1P_CNT;
    } else if (e < W1P_CNT + W2P_CNT + WCP_CNT) {
        src = Wc; dst = ws + WCP_OFF; K = 128; N = 64; NT = 4; NS = 4; r = e - W1P_CNT - W2P_CNT;
    } else {
        src = Wd; dst = ws + WDP_OFF; K = 64; N = 16; NT = 1; NS = 2; r = e - W1P_CNT - W2P_CNT - WCP_CNT;
    }
    int j = r & 7, l = (r >> 3) & 63;
    int rest = r >> 9;
    int s  = rest % NS; rest /= NS;
    int nt = rest % NT; rest /= NT;
    int a  = rest;
    int k = s * 32 + (l >> 4) * 8 + j;
    int n = nt * 16 + (l & 15);
    dst[r] = (_Float16)src[((size_t)a * K + k) * N + n];
}

// ---------------------------------------------------------------------------
// Encoder: h = relu(relu(obs@W1+b1)@W2+b2) -> ws (f16, [b][a][c])
// grid (8, 32), block 256 (4 waves), 1 block/CU. Per-wave pipeline:
//   prologue: all W1/W2 fragments -> VGPRs (keep-alive pinned); issue DMA(0).
//   tile t: [lgkmcnt(0); issue DMA(t+1); vmcnt(peel)] -> GEMM1 from swizzled
//   f32 slab -> x (f16) aliased over consumed slab -> GEMM2 -> coalesced
//   b128 h stores. Loop has NO global loads: vmcnt counting is exact.
// ---------------------------------------------------------------------------
extern "C" __global__ __launch_bounds__(256, 1)
void enc_kernel(const float* __restrict__ obs,
                const float* __restrict__ b1,
                const float* __restrict__ b2,
                const _Float16* __restrict__ W1p,
                const _Float16* __restrict__ W2p,
                _Float16* __restrict__ hws)
{
    extern __shared__ char smem[];

    const int tid  = threadIdx.x;
    const int a    = blockIdx.y;
    const int w    = tid >> 6, l = tid & 63;
    const int lm   = l & 15, lq = l >> 4;
    const int hrow = l >> 5;          // DMA: row parity within 2-row chunk
    const int cch  = l & 31;          // DMA: stored 16B-chunk index
    char* SBA = smem + w * ENC_SLAB;  // this wave's two 8KB buffers
    char* SBB = SBA + 8192;

    const int rowb = blockIdx.x * ENC_BROWS + w * ENC_WROWS;  // wave row base
    const char* ob = (const char*)obs + (size_t)rowb * (NA * NOBS * 4) + (size_t)a * (NOBS * 4);

    // ---- prologue: ALL weight fragments + biases -> registers, pinned.
    floatx4 w1r[8][4], w2r[4][4];
    #pragma unroll
    for (int nt = 0; nt < 8; ++nt)
        #pragma unroll
        for (int s = 0; s < 4; ++s)
            w1r[nt][s] = *(const floatx4*)&W1p[(((a * 8 + nt) * 4 + s) * 512) + l * 8];
    #pragma unroll
    for (int nt = 0; nt < 4; ++nt)
        #pragma unroll
        for (int s = 0; s < 4; ++s)
            w2r[nt][s] = *(const floatx4*)&W2p[(((a * 4 + nt) * 4 + s) * 512) + l * 8];
    float b1v[8], b2v[4];
    #pragma unroll
    for (int nt = 0; nt < 8; ++nt) b1v[nt] = b1[a * NH1 + nt * 16 + lm];
    #pragma unroll
    for (int nt = 0; nt < 4; ++nt) b2v[nt] = b2[a * HXX + nt * 16 + lm];

    // Fake-use every preloaded value: forces the compiler to place its
    // vmcnt waits HERE (pre-loop), never inside the pipelined loop.
    #pragma unroll
    for (int nt = 0; nt < 8; ++nt)
        #pragma unroll
        for (int s = 0; s < 4; ++s) asm volatile("" :: "v"(w1r[nt][s]));
    #pragma unroll
    for (int nt = 0; nt < 4; ++nt)
        #pragma unroll
        for (int s = 0; s < 4; ++s) asm volatile("" :: "v"(w2r[nt][s]));
    #pragma unroll
    for (int nt = 0; nt < 8; ++nt) asm volatile("" :: "v"(b1v[nt]));
    #pragma unroll
    for (int nt = 0; nt < 4; ++nt) asm volatile("" :: "v"(b2v[nt]));

    // t-invariant per-lane DMA byte offsets (8 VGPRs)
    int dmaoff[8];
    #pragma unroll
    for (int i = 0; i < 8; ++i) {
        const int r = 2 * i + hrow;
        dmaoff[i] = r * (NA * NOBS * 4) + ((cch ^ (r & 7)) << 4);
    }

    auto issue = [&](int t, char* dst) {
        const char* bt = ob + (size_t)t * (16 * NA * NOBS * 4);
        #pragma unroll
        for (int i = 0; i < 8; ++i)
            __builtin_amdgcn_global_load_lds((gas1p)(bt + dmaoff[i]),
                                             (las3p)(dst + i * 1024), 16, 0, 0);
    };

    issue(0, SBA);

    for (int t = 0; t < ENC_TILES; ++t) {
        char* SBp = (t & 1) ? SBB : SBA;   // current tile's slab (obs -> x -> h)
        char* SBn = (t & 1) ? SBA : SBB;   // next tile's slab

        if (t < ENC_TILES - 1) {
            // epilogue(t-1) LDS reads of SBn must be complete before DMA lands
            asm volatile("s_waitcnt lgkmcnt(0)" ::: "memory");
            issue(t + 1, SBn);
            if (t == 0) asm volatile("s_waitcnt vmcnt(8)" ::: "memory");
            else        asm volatile("s_waitcnt vmcnt(10)" ::: "memory"); // leaves stores(t-1)+DMA(t+1)
        } else {
            asm volatile("s_waitcnt vmcnt(2)" ::: "memory");              // leaves stores(t-1)
        }
        __builtin_amdgcn_sched_barrier(0);

        _Float16* X = (_Float16*)SBp;      // x/h alias over consumed obs slab
        const int rx = lm & 7;

        // ---- GEMM1: x = obs @ W1 (1 m-tile x 8 n-tiles, K=128)
        floatx4 acc1[8];
        #pragma unroll
        for (int nt = 0; nt < 8; ++nt) acc1[nt] = (floatx4){0.f, 0.f, 0.f, 0.f};
        #pragma unroll
        for (int s = 0; s < 4; ++s) {
            const int c0 = s * 8 + lq * 2;
            floatx4 f0 = *(const floatx4*)(SBp + lm * 512 + (((c0    ) ^ rx) << 4));
            floatx4 f1 = *(const floatx4*)(SBp + lm * 512 + (((c0 + 1) ^ rx) << 4));
            half8 af;
            af[0] = (_Float16)f0[0]; af[1] = (_Float16)f0[1];
            af[2] = (_Float16)f0[2]; af[3] = (_Float16)f0[3];
            af[4] = (_Float16)f1[0]; af[5] = (_Float16)f1[1];
            af[6] = (_Float16)f1[2]; af[7] = (_Float16)f1[3];
            #pragma unroll
            for (int nt = 0; nt < 8; ++nt)
                acc1[nt] = MFMA16(af, H8(w1r[nt][s]), acc1[nt]);
        }
        // x (relu) into the consumed slab, transposed layout [row][136]
        #pragma unroll
        for (int nt = 0; nt < 8; ++nt)
            #pragma unroll
            for (int v = 0; v < 4; ++v) {
                float xv = fmaxf(acc1[nt][v] + b1v[nt], 0.f);
                X[(lq * 4 + v) * 136 + nt * 16 + lm] = (_Float16)xv;
            }

        // ---- GEMM2: h = X @ W2 (1 m-tile x 4 n-tiles)
        floatx4 acc2[4];
        #pragma unroll
        for (int nt = 0; nt < 4; ++nt) acc2[nt] = (floatx4){0.f, 0.f, 0.f, 0.f};
        #pragma unroll
        for (int s = 0; s < 4; ++s) {
            half8 af2 = *(const half8*)&X[lm * 136 + s * 32 + lq * 8];
            #pragma unroll
            for (int nt = 0; nt < 4; ++nt)
                acc2[nt] = MFMA16(af2, H8(w2r[nt][s]), acc2[nt]);
        }
        #pragma unroll
        for (int nt = 0; nt < 4; ++nt)
            #pragma unroll
            for (int v = 0; v < 4; ++v) {
                float hv = fmaxf(acc2[nt][v] + b2v[nt], 0.f);
                X[(lq * 4 + v) * 136 + nt * 16 + lm] = (_Float16)hv;
            }

        // ---- epilogue: coalesced b128 h stores (16 rows x 8 chunks)
        {
            const int rr = l >> 2, cc = l & 3;
            _Float16* hb = hws + ((size_t)(rowb + t * 16 + rr) * NA + a) * HXX;
            #pragma unroll
            for (int q2 = 0; q2 < 2; ++q2) {
                const int chunk = cc + 4 * q2;
                half8 hv8 = *(const half8*)&X[rr * 136 + chunk * 8];
                *(half8*)&hb[chunk * 8] = hv8;
            }
        }
    }
}

// ---------------------------------------------------------------------------
// Decoder: comm masked-mean + tanh([h|comm]@Wc+bc) @ Wd + bd.
// grid 512, block 512 (8 waves). Block = 16 batch rows x 32 agents.
// H (LDS): [row][agent*64+c], row slab HSTR halfs. Wave w owns agents
// 4w..4w+3, full 16-row m-tiles. comm lives in A-frag registers (hacc):
// frag_comm(i,s) = sum_j Mn[i][j] * frag_h(j, s-2)  (fragment linearity).
// h2 in C-layout regs across nt loop; single LDS write for Wd GEMM.
// ---------------------------------------------------------------------------
extern "C" __global__ __launch_bounds__(512)
void dec_kernel(const _Float16* __restrict__ hws,
                const float* __restrict__ MnG,
                const float* __restrict__ bc,
                const float* __restrict__ bd,
                const _Float16* __restrict__ Wcp,
                const _Float16* __restrict__ Wdp,
                float* __restrict__ out)
{
    extern __shared__ char smem[];
    _Float16* H = (_Float16*)smem;   // 16 x HSTR

    const int t  = threadIdx.x;
    const int b0 = blockIdx.x * 16;

    {   // stage h tile: 16 rows x 32 ag x 64 ch = 4096 uint4, coalesced
        const uint4* src = (const uint4*)(hws + (size_t)b0 * NA * HXX);
        #pragma unroll
        for (int it = 0; it < 8; ++it) {
            int idx = it * 512 + t;
            int row = idx >> 8, rem = idx & 255;
            *(uint4*)&H[row * HSTR + rem * 8] = src[idx];
        }
    }
    __syncthreads();

    const int w = t >> 6, l = t & 63, lm = l & 15, lq = l >> 4;

    // ---- comm into A-frag registers (reads ALL rows; barrier after)
    half8 hacc[4][2];
    #pragma unroll
    for (int g = 0; g < 4; ++g)
        #pragma unroll
        for (int sb = 0; sb < 2; ++sb)
            #pragma unroll
            for (int q = 0; q < 8; ++q) hacc[g][sb][q] = (_Float16)0.f;

    #pragma unroll 4
    for (int j = 0; j < NA; ++j) {
        half8 v0 = *(const half8*)&H[lm * HSTR + j * 64 + lq * 8];
        half8 v1 = *(const half8*)&H[lm * HSTR + j * 64 + 32 + lq * 8];
        #pragma unroll
        for (int g = 0; g < 4; ++g) {
            int ag = __builtin_amdgcn_readfirstlane(w * 4 + g);
            _Float16 mh = (_Float16)MnG[ag * NA + j];   // s_load, wave-uniform
            hacc[g][0] += v0 * mh;
            hacc[g][1] += v1 * mh;
        }
    }
    __syncthreads();   // all comm reads done before any h2 overwrite
    // From here each wave touches only its own agents' columns.

    // ---- Wc GEMM per n-tile; h2 kept in C-layout regs
    half4 h2r[4][4];
    #pragma unroll
    for (int nt = 0; nt < 4; ++nt) {
        floatx4 acc[4];
        #pragma unroll
        for (int g = 0; g < 4; ++g) acc[g] = (floatx4){0.f, 0.f, 0.f, 0.f};
        #pragma unroll
        for (int s = 0; s < 4; ++s) {
            #pragma unroll
            for (int g = 0; g < 4; ++g) {
                int ag = w * 4 + g;
                half8 af = (s < 2)
                    ? *(const half8*)&H[lm * HSTR + ag * 64 + s * 32 + lq * 8]
                    : hacc[g][s - 2];
                half8 bf = *(const half8*)&Wcp[(((ag * 4 + nt) * 4 + s) * 512) + l * 8];
                acc[g] = MFMA16(af, bf, acc[g]);
            }
        }
        #pragma unroll
        for (int g = 0; g < 4; ++g) {
            int ag = w * 4 + g;
            float bcv = bc[ag * HXX + nt * 16 + lm];
            #pragma unroll
            for (int v = 0; v < 4; ++v)
                h2r[g][nt][v] = (_Float16)fast_tanh(acc[g][v] + bcv);
        }
    }

    // write h2 over own agents' h (all Wc reads of those columns are done)
    #pragma unroll
    for (int g = 0; g < 4; ++g) {
        int ag = w * 4 + g;
        #pragma unroll
        for (int nt = 0; nt < 4; ++nt)
            #pragma unroll
            for (int v = 0; v < 4; ++v)
                H[(lq * 4 + v) * HSTR + ag * 64 + nt * 16 + lm] = h2r[g][nt][v];
    }
    // wave-internal LDS RAW -> compiler lgkmcnt; no cross-wave access

    // ---- Wd GEMM: K=64, N=16
    floatx4 acc3[4];
    #pragma unroll
    for (int g = 0; g < 4; ++g) acc3[g] = (floatx4){0.f, 0.f, 0.f, 0.f};
    #pragma unroll
    for (int s = 0; s < 2; ++s) {
        #pragma unroll
        for (int g = 0; g < 4; ++g) {
            int ag = w * 4 + g;
            half8 af = *(const half8*)&H[lm * HSTR + ag * 64 + s * 32 + lq * 8];
            half8 bf = *(const half8*)&Wdp[((ag * 2 + s) * 512) + l * 8];
            acc3[g] = MFMA16(af, bf, acc3[g]);
        }
    }

    #pragma unroll
    for (int g = 0; g < 4; ++g) {
        int ag = w * 4 + g;
        float bdv = bd[ag * NACT + lm];
        #pragma unroll
        for (int v = 0; v < 4; ++v) {
            int row = lq * 4 + v;
            out[((size_t)(b0 + row) * NA + ag) * NACT + lm] = acc3[g][v] + bdv;
        }
    }
}

// ---------------------------------------------------------------------------
extern "C" void kernel_launch(void* const* d_in, const int* in_sizes, int n_in,
                              void* d_out, int out_size, void* d_ws, size_t ws_size,
                              hipStream_t stream)
{
    const float* obs = (const float*)d_in[0];
    const float* W1  = (const float*)d_in[1];
    const float* b1  = (const float*)d_in[2];
    const float* W2  = (const float*)d_in[3];
    const float* b2  = (const float*)d_in[4];
    const float* Wc  = (const float*)d_in[7];
    const float* bc  = (const float*)d_in[8];
    const float* Wd  = (const float*)d_in[9];
    const float* bd  = (const float*)d_in[10];
    const int*   cm  = (const int*)d_in[11];

    float*    outp = (float*)d_out;
    _Float16* ws   = (_Float16*)d_ws;

    _Float16* hws = ws + HWS_OFF;
    _Float16* W1p = ws + W1P_OFF;
    _Float16* W2p = ws + W2P_OFF;
    _Float16* Wcp = ws + WCP_OFF;
    _Float16* Wdp = ws + WDP_OFF;
    const float* MnG = (const float*)(ws + MN_OFF);

    hipLaunchKernelGGL(pack_kernel, dim3((PACK_TOTAL + NA * NA + 255) / 256),
                       dim3(256), 0, stream, W1, W2, Wc, Wd, cm, ws);

    (void)hipFuncSetAttribute((const void*)enc_kernel,
                              hipFuncAttributeMaxDynamicSharedMemorySize, ENC_LDS);
    hipLaunchKernelGGL(enc_kernel, dim3(NB / ENC_BROWS, NA), dim3(256), ENC_LDS,
                       stream, obs, b1, b2, W1p, W2p, hws);

    (void)hipFuncSetAttribute((const void*)dec_kernel,
                              hipFuncAttributeMaxDynamicSharedMemorySize, DEC_LDS);
    hipLaunchKernelGGL(dec_kernel, dim3(NB / 16), dim3(512), DEC_LDS, stream,
                       hws, MnG, bc, bd, Wcp, Wdp, outp);
}